// Round 10
// baseline (321.919 us; speedup 1.0000x reference)
//
#include <hip/hip_runtime.h>
#include <hip/hip_bf16.h>
#include <stdint.h>

#define B_DIM 4096
#define P_DIMC 1024
#define H_DIMC 2048
#define X_DIMC 1024
#define K_DIM 4096   // P + H + X
#define N_DIM 8192   // 4*H (gate-minor packed: n = (h>>4)*64 + gate*16 + (h&15))

#define BM 256
#define BN 256
#define BK 64
#define NT (K_DIM / BK)   // 64 K-tiles

typedef __attribute__((ext_vector_type(8))) short bf16x8;
typedef __attribute__((ext_vector_type(4))) float f32x4;

__device__ __forceinline__ unsigned short f2bf(float f) {
  union { float f; unsigned u; } v; v.f = f;
  unsigned u = v.u;
  u += 0x7FFFu + ((u >> 16) & 1u);   // round-to-nearest-even
  return (unsigned short)(u >> 16);
}

__device__ __forceinline__ float sigm(float x) { return 1.f / (1.f + __expf(-x)); }
__device__ __forceinline__ float tanh_fast(float x) {
  float e = __expf(2.f * x);
  return 1.f - 2.f / (e + 1.f);      // safe at +/- inf
}

__device__ __forceinline__ void gl_lds16(const void* g, void* l) {
  __builtin_amdgcn_global_load_lds((const __attribute__((address_space(1))) void*)g,
                                   (__attribute__((address_space(3))) void*)l, 16, 0, 0);
}

// ---------------- pack A = [P | hidden | ext] -> bf16 [B][K] ----------------
__global__ void pack_a_kernel(const float* __restrict__ P, const float* __restrict__ Hd,
                              const float* __restrict__ X, unsigned short* __restrict__ A) {
  const int total = B_DIM * (K_DIM / 4);
  for (int idx = blockIdx.x * blockDim.x + threadIdx.x; idx < total;
       idx += gridDim.x * blockDim.x) {
    int row = idx >> 10;
    int col = (idx & 1023) << 2;
    const float* src; int off;
    if (col < P_DIMC)                { src = P;  off = row * P_DIMC + col; }
    else if (col < P_DIMC + H_DIMC)  { src = Hd; off = row * H_DIMC + (col - P_DIMC); }
    else                             { src = X;  off = row * X_DIMC + (col - P_DIMC - H_DIMC); }
    float4 v = *(const float4*)(src + off);
    ushort4 o;
    o.x = f2bf(v.x); o.y = f2bf(v.y); o.z = f2bf(v.z); o.w = f2bf(v.w);
    *(ushort4*)(A + (size_t)row * K_DIM + col) = o;
  }
}

// ------- pack Wbig [N][K] bf16, gate-minor at 16 granularity ----------------
// row n holds weights for gate=(n>>4)&3, h=((n>>6)<<4)|(n&15)
struct WPtrs {
  const float *pi, *pf, *pg, *po;
  const float *hi, *hf, *hg, *ho;
  const float *xi, *xf, *xg, *xo;
};

__global__ void pack_w_kernel(WPtrs w, unsigned short* __restrict__ Wo) {
  const int total = N_DIM * (K_DIM / 4);
  for (int idx = blockIdx.x * blockDim.x + threadIdx.x; idx < total;
       idx += gridDim.x * blockDim.x) {
    int n = idx >> 10;
    int col = (idx & 1023) << 2;
    int gate = (n >> 4) & 3;
    int h = ((n >> 6) << 4) | (n & 15);
    const float* src; int off;
    if (col < P_DIMC) {
      src = gate == 0 ? w.pi : gate == 1 ? w.pf : gate == 2 ? w.pg : w.po;
      off = h * P_DIMC + col;
    } else if (col < P_DIMC + H_DIMC) {
      src = gate == 0 ? w.hi : gate == 1 ? w.hf : gate == 2 ? w.hg : w.ho;
      off = h * H_DIMC + (col - P_DIMC);
    } else {
      src = gate == 0 ? w.xi : gate == 1 ? w.xf : gate == 2 ? w.xg : w.xo;
      off = h * X_DIMC + (col - P_DIMC - H_DIMC);
    }
    float4 v = *(const float4*)(src + off);
    ushort4 o;
    o.x = f2bf(v.x); o.y = f2bf(v.y); o.z = f2bf(v.z); o.w = f2bf(v.w);
    *(ushort4*)(Wo + (size_t)n * K_DIM + col) = o;
  }
}

// ------ fused GEMM: 256x256, BK=64, corrected m201 8-phase schedule ---------
// dbuf[2] x row-half[2]; per tile 4 phases {reads(8/4/8/4) + 1 half stage +
// barrier + lgkm0 + 16 MFMA + barrier}; stage rotation Bh1,Ah0,Ah1,Bh0(t+2)
// gives >=1.5-phase lead; ONE vmcnt(4) per tile (0 at last).
__global__ __launch_bounds__(512, 1) void gemm_lstm_kernel(
    const unsigned short* __restrict__ A, const unsigned short* __restrict__ W,
    const float* __restrict__ cell,
    const float* __restrict__ bpi, const float* __restrict__ bpf,
    const float* __restrict__ bpg, const float* __restrict__ bpo,
    float* __restrict__ out) {
  // [slot][half][128 rows x 64 k] = 16 KB each; A 64 KB + B 64 KB = 128 KiB
  __shared__ __align__(16) short As[2][2][8192];
  __shared__ __align__(16) short Bs[2][2][8192];

  const int T = threadIdx.x;
  const int wave = T >> 6, lane = T & 63;
  const int wm = wave >> 2, wn = wave & 3;     // 2 x 4 wave grid
  const int wbh = wn >> 1;                     // B col-half this wave reads

  // XCD-aware mapping: 512 blocks, XCD x gets an 8x8 tile patch
  const int x = blockIdx.x & 7, local = blockIdx.x >> 3;
  const int bm = (x & 1) * 8 + (local >> 3);   // 0..15
  const int bn = (x >> 1) * 8 + (local & 7);   // 0..31

  // ---- staging: linear LDS dest, chunk-rotated global source ----
  // row r (128B = 8 chunks of 16B): logical chunk c stored at slot (c + r&7)&7
  const int rS = T >> 3;                        // 0..63 (inst1: +64)
  const int cg = ((T & 7) - (rS & 7)) & 7;
  const unsigned short* aS0 = A + (size_t)(bm * BM + rS) * K_DIM + cg * 8;
  const unsigned short* aS1 = A + (size_t)(bm * BM + 128 + rS) * K_DIM + cg * 8;
  const unsigned short* bS0 = W + (size_t)(bn * BN + rS) * K_DIM + cg * 8;
  const unsigned short* bS1 = W + (size_t)(bn * BN + 128 + rS) * K_DIM + cg * 8;
  const int dOff = T * 8;                       // shorts; +4096 for rows 64-127

#define STG(SRCP, KOFF, DSTBASE)                                              \
  { const unsigned short* s_ = (SRCP) + (KOFF);                               \
    gl_lds16(s_, (DSTBASE) + dOff);                                           \
    gl_lds16(s_ + (size_t)64 * K_DIM, (DSTBASE) + 4096 + dOff); }

  // ---- fragment read addressing (within a half-buffer) ----
  const int lrow = lane & 15, kgrp = lane >> 4;
  const int rb = lrow & 7;
  const int sk0 = ((kgrp + rb) & 7) * 8;        // k32=0 chunk slot (shorts)
  const int sk1 = ((kgrp + 4 + rb) & 7) * 8;    // k32=1 chunk slot
  const int aRowB = lrow * 64;                  // A: row lrow (+ mf*16 rows via *1024)
  const int bRowB = ((wn & 1) * 64 + lrow) * 64;

  f32x4 acc[8][4] = {};
  bf16x8 av[4], bv[4];

  // ---- prologue: stage tile0 (Bh0,Bh1,Ah0,Ah1) + Bh0(1); wait tile0 ----
  STG(bS0, 0, &Bs[0][0][0])
  STG(bS1, 0, &Bs[0][1][0])
  STG(aS0, 0, &As[0][0][0])
  STG(aS1, 0, &As[0][1][0])
  STG(bS0, BK, &Bs[1][0][0])
  asm volatile("s_waitcnt vmcnt(2)" ::: "memory");
  __builtin_amdgcn_s_barrier();

#define FENCE_PRE()                                                           \
  __builtin_amdgcn_sched_barrier(0);                                          \
  __builtin_amdgcn_s_barrier();                                               \
  asm volatile("s_waitcnt lgkmcnt(0)" ::: "memory");                          \
  __builtin_amdgcn_sched_barrier(0);
#define FENCE_POST()                                                          \
  __builtin_amdgcn_s_setprio(0);                                              \
  __builtin_amdgcn_sched_barrier(0);                                          \
  __builtin_amdgcn_s_barrier();

  for (int t = 0; t < NT; ++t) {
    const int cur = t & 1, nxt = cur ^ 1;
    const short* A_w = &As[cur][wm][0];
    const short* B_w = &Bs[cur][wbh][0];
    const int k1 = (t + 1) * BK, k2 = (t + 2) * BK;

    // ---- p0: av(mf0-3,k0) + bv(k0); stage Bh1(t+1); MFMA mf0-3 @ k0 ----
#pragma unroll
    for (int i = 0; i < 4; ++i) av[i] = *(const bf16x8*)(A_w + aRowB + i * 1024 + sk0);
#pragma unroll
    for (int j = 0; j < 4; ++j) bv[j] = *(const bf16x8*)(B_w + bRowB + j * 1024 + sk0);
    if (t < NT - 1) STG(bS1, k1, &Bs[nxt][1][0])
    // single derived vmcnt per tile: youngest required half = Ah1(t)@(t-1)p2;
    // issued after it: Bh0(t+1)@(t-1)p3 [2] + Bh1(t+1)@p0 [2] = 4.
    if (t < NT - 1) { asm volatile("s_waitcnt vmcnt(4)" ::: "memory"); }
    else            { asm volatile("s_waitcnt vmcnt(0)" ::: "memory"); }
    FENCE_PRE()
    __builtin_amdgcn_s_setprio(1);
#pragma unroll
    for (int i = 0; i < 4; ++i)
#pragma unroll
      for (int j = 0; j < 4; ++j)
        acc[i][j] = __builtin_amdgcn_mfma_f32_16x16x32_bf16(av[i], bv[j], acc[i][j], 0, 0, 0);
    FENCE_POST()

    // ---- p1: av(mf4-7,k0); stage Ah0(t+1); MFMA mf4-7 @ k0 (bv held) ----
#pragma unroll
    for (int i = 0; i < 4; ++i) av[i] = *(const bf16x8*)(A_w + aRowB + (4 + i) * 1024 + sk0);
    if (t < NT - 1) STG(aS0, k1, &As[nxt][0][0])
    FENCE_PRE()
    __builtin_amdgcn_s_setprio(1);
#pragma unroll
    for (int i = 0; i < 4; ++i)
#pragma unroll
      for (int j = 0; j < 4; ++j)
        acc[4 + i][j] = __builtin_amdgcn_mfma_f32_16x16x32_bf16(av[i], bv[j], acc[4 + i][j], 0, 0, 0);
    FENCE_POST()

    // ---- p2: av(mf4-7,k1) + bv(k1); stage Ah1(t+1); MFMA mf4-7 @ k1 ----
#pragma unroll
    for (int i = 0; i < 4; ++i) av[i] = *(const bf16x8*)(A_w + aRowB + (4 + i) * 1024 + sk1);
#pragma unroll
    for (int j = 0; j < 4; ++j) bv[j] = *(const bf16x8*)(B_w + bRowB + j * 1024 + sk1);
    if (t < NT - 1) STG(aS1, k1, &As[nxt][1][0])
    FENCE_PRE()
    __builtin_amdgcn_s_setprio(1);
#pragma unroll
    for (int i = 0; i < 4; ++i)
#pragma unroll
      for (int j = 0; j < 4; ++j)
        acc[4 + i][j] = __builtin_amdgcn_mfma_f32_16x16x32_bf16(av[i], bv[j], acc[4 + i][j], 0, 0, 0);
    FENCE_POST()

    // ---- p3: av(mf0-3,k1); stage Bh0(t+2) into cur (own Bh0 freed at p2) ----
#pragma unroll
    for (int i = 0; i < 4; ++i) av[i] = *(const bf16x8*)(A_w + aRowB + i * 1024 + sk1);
    if (t < NT - 2) STG(bS0, k2, &Bs[cur][0][0])
    FENCE_PRE()
    __builtin_amdgcn_s_setprio(1);
#pragma unroll
    for (int i = 0; i < 4; ++i)
#pragma unroll
      for (int j = 0; j < 4; ++j)
        acc[i][j] = __builtin_amdgcn_mfma_f32_16x16x32_bf16(av[i], bv[j], acc[i][j], 0, 0, 0);
    FENCE_POST()
  }
#undef STG
#undef FENCE_PRE
#undef FENCE_POST

  // ---- fused LSTM epilogue (per-lane: n-frags 0..3 = gates i,f,g,o of h) ---
  const int h = bn * 64 + wn * 16 + lrow;
  const float bi = bpi[h], bf_ = bpf[h], bg = bpg[h], bo = bpo[h];
  const int rbase = bm * BM + wm * 128 + kgrp * 4;
#pragma unroll
  for (int mf = 0; mf < 8; ++mf) {
#pragma unroll
    for (int r = 0; r < 4; ++r) {
      const int brow = rbase + mf * 16 + r;
      float gi = acc[mf][0][r] + bi;
      float gf = acc[mf][1][r] + bf_;
      float gg = acc[mf][2][r] + bg;
      float go = acc[mf][3][r] + bo;
      float i_ = sigm(gi), f_ = sigm(gf), g_ = tanh_fast(gg), o_ = sigm(go);
      float cold = cell[(size_t)brow * H_DIMC + h];
      float cn = f_ * cold + i_ * g_;
      out[(size_t)brow * H_DIMC + h] = o_ * tanh_fast(cn);
      out[(size_t)B_DIM * H_DIMC + (size_t)brow * H_DIMC + h] = cn;
    }
  }
}

extern "C" void kernel_launch(void* const* d_in, const int* in_sizes, int n_in,
                              void* d_out, int out_size, void* d_ws, size_t ws_size,
                              hipStream_t stream) {
  const float* P    = (const float*)d_in[0];
  const float* Hd   = (const float*)d_in[1];
  const float* cell = (const float*)d_in[2];
  const float* X    = (const float*)d_in[3];
  WPtrs w;
  w.pi = (const float*)d_in[4];   const float* bpi = (const float*)d_in[5];
  w.pf = (const float*)d_in[6];   const float* bpf = (const float*)d_in[7];
  w.pg = (const float*)d_in[8];   const float* bpg = (const float*)d_in[9];
  w.po = (const float*)d_in[10];  const float* bpo = (const float*)d_in[11];
  w.hi = (const float*)d_in[12];  w.hf = (const float*)d_in[13];
  w.hg = (const float*)d_in[14];  w.ho = (const float*)d_in[15];
  w.xi = (const float*)d_in[16];  w.xf = (const float*)d_in[17];
  w.xg = (const float*)d_in[18];  w.xo = (const float*)d_in[19];

  unsigned short* Abf = (unsigned short*)d_ws;                 // 32 MiB
  unsigned short* Wbf = Abf + (size_t)B_DIM * K_DIM;           // 64 MiB

  pack_a_kernel<<<2048, 256, 0, stream>>>(P, Hd, X, Abf);
  pack_w_kernel<<<2048, 256, 0, stream>>>(w, Wbf);
  gemm_lstm_kernel<<<512, 512, 0, stream>>>(Abf, Wbf, cell, bpi, bpf, bpg, bpo,
                                            (float*)d_out);
}